// Round 5
// baseline (484.087 us; speedup 1.0000x reference)
//
#include <hip/hip_runtime.h>

typedef __bf16 bf16;
typedef __bf16 bf16x8 __attribute__((ext_vector_type(8)));
typedef float  f32x4  __attribute__((ext_vector_type(4)));
typedef unsigned u32x4 __attribute__((ext_vector_type(4)));

#define B_  8
#define N_  2048
#define D_  512
#define H_  8
#define DH_ 64
static constexpr float SC2 = 0.18033688011112042f; // (1/8) * log2(e)

#if defined(__has_builtin)
#if __has_builtin(__builtin_amdgcn_exp2f)
#define EXP2(x) __builtin_amdgcn_exp2f(x)
#else
#define EXP2(x) exp2f(x)
#endif
#else
#define EXP2(x) exp2f(x)
#endif

#if defined(__has_builtin)
#if __has_builtin(__builtin_amdgcn_permlane32_swap) && __has_builtin(__builtin_amdgcn_permlane16_swap)
#define HAVE_PLSWAP 1
#endif
#endif

__device__ __forceinline__ f32x4 mfma16(bf16x8 a, bf16x8 b, f32x4 c) {
  return __builtin_amdgcn_mfma_f32_16x16x32_bf16(a, b, c, 0, 0, 0);
}

__device__ __forceinline__ void gload_lds16(const void* g, void* l) {
  __builtin_amdgcn_global_load_lds((__attribute__((address_space(1))) void*)g,
                                   (__attribute__((address_space(3))) void*)l, 16, 0, 0);
}

__device__ __forceinline__ unsigned cvt_pk_bf16(float lo, float hi) {
  unsigned r;
  asm("v_cvt_pk_bf16_f32 %0, %1, %2" : "=v"(r) : "v"(lo), "v"(hi));
  return r;
}

// ---- convert x (f32) -> bf16, 8 elems/thread ----
__global__ void k_cvt_x(const float* __restrict__ x, bf16* __restrict__ xb) {
  int i = blockIdx.x * blockDim.x + threadIdx.x;
  const float4* p = (const float4*)x;
  float4 a = p[2*i], b = p[2*i+1];
  bf16x8 o;
  o[0]=(bf16)a.x; o[1]=(bf16)a.y; o[2]=(bf16)a.z; o[3]=(bf16)a.w;
  o[4]=(bf16)b.x; o[5]=(bf16)b.y; o[6]=(bf16)b.z; o[7]=(bf16)b.w;
  ((bf16x8*)xb)[i] = o;
}

// ---- transpose-convert one 512x512 f32 weight -> bf16 W^T ----
__global__ void k_wt(const float* __restrict__ w, bf16* __restrict__ wt) {
  __shared__ float t[64][65];
  const int c0 = blockIdx.x * 64, k0 = blockIdx.y * 64;
  const int r = threadIdx.x >> 2, q4 = (threadIdx.x & 3) * 16;
#pragma unroll
  for (int j = 0; j < 16; j += 4) {
    float4 v = *(const float4*)(w + (k0 + r) * 512 + c0 + q4 + j);
    t[r][q4+j] = v.x; t[r][q4+j+1] = v.y; t[r][q4+j+2] = v.z; t[r][q4+j+3] = v.w;
  }
  __syncthreads();
  const int c = threadIdx.x >> 2, kq = (threadIdx.x & 3) * 16;
  bf16x8 o0, o1;
#pragma unroll
  for (int j = 0; j < 8; ++j) { o0[j] = (bf16)t[kq+j][c]; o1[j] = (bf16)t[kq+8+j][c]; }
  *(bf16x8*)(wt + (c0 + c) * 512 + k0 + kq) = o0;
  *(bf16x8*)(wt + (c0 + c) * 512 + k0 + kq + 8) = o1;
}

// ---- 128x128 tile GEMM, K=512 ----
template<int MODE>
__global__ void k_gemm(const bf16* __restrict__ A, const bf16* __restrict__ Bt,
                       bf16* __restrict__ qo, bf16* __restrict__ ko, bf16* __restrict__ vo,
                       float* __restrict__ outp, const float* __restrict__ bo) {
  __shared__ bf16 lA[128 * 64];
  __shared__ bf16 lB[128 * 64];
  const int tid = threadIdx.x;
  const int wid = tid >> 6, lane = tid & 63;
  const int l15 = lane & 15, lq = lane >> 4;
  const int wr = wid >> 1, wc = wid & 1;
  const long long rowtile = (long long)blockIdx.x * 128;
  const long long coltile = (long long)blockIdx.y * 128;

  const bf16* gA[4]; const bf16* gB[4];
  bf16* lAc[4]; bf16* lBc[4];
#pragma unroll
  for (int i = 0; i < 4; ++i) {
    int ci = wid * 4 + i;
    int row = ci * 8 + (lane >> 3);
    int c8 = (lane & 7) ^ (row & 7);
    gA[i] = A + (rowtile + row) * 512 + c8 * 8;
    gB[i] = Bt + (coltile + row) * 512 + c8 * 8;
    lAc[i] = &lA[ci * 512];
    lBc[i] = &lB[ci * 512];
  }
  unsigned aoff[4][2], boff[4][2];
#pragma unroll
  for (int mi = 0; mi < 4; ++mi) {
#pragma unroll
    for (int ks = 0; ks < 2; ++ks) {
      int R = l15 + 16 * mi + 64 * wr;
      aoff[mi][ks] = R * 128 + ((((ks << 2) | lq) ^ (R & 7)) << 4);
      int Rb = l15 + 16 * mi + 64 * wc;
      boff[mi][ks] = Rb * 128 + ((((ks << 2) | lq) ^ (Rb & 7)) << 4);
    }
  }
  f32x4 acc[4][4] = {};
  for (int kt = 0; kt < 8; ++kt) {
#pragma unroll
    for (int i = 0; i < 4; ++i) gload_lds16(gA[i], lAc[i]);
#pragma unroll
    for (int i = 0; i < 4; ++i) gload_lds16(gB[i], lBc[i]);
#pragma unroll
    for (int i = 0; i < 4; ++i) { gA[i] += 64; gB[i] += 64; }
    __syncthreads();
#pragma unroll
    for (int ks = 0; ks < 2; ++ks) {
      bf16x8 af[4], bfr[4];
#pragma unroll
      for (int mi = 0; mi < 4; ++mi) af[mi] = *(const bf16x8*)((const char*)lA + aoff[mi][ks]);
#pragma unroll
      for (int nf = 0; nf < 4; ++nf) bfr[nf] = *(const bf16x8*)((const char*)lB + boff[nf][ks]);
#pragma unroll
      for (int mi = 0; mi < 4; ++mi)
#pragma unroll
        for (int nf = 0; nf < 4; ++nf)
          acc[mi][nf] = mfma16(af[mi], bfr[nf], acc[mi][nf]);
    }
    __syncthreads();
  }
  if (MODE == 0) {
#pragma unroll
    for (int nf = 0; nf < 4; ++nf) {
      const int col = (int)coltile + 64 * wc + nf * 16 + l15;
      const int mat = col >> 9, c5 = col & 511, hh = c5 >> 6, dh = c5 & 63;
#pragma unroll
      for (int mi = 0; mi < 4; ++mi) {
#pragma unroll
        for (int r = 0; r < 4; ++r) {
          const int R = (int)rowtile + 64 * wr + mi * 16 + lq * 4 + r;
          const int bb = R >> 11, n = R & 2047;
          const bf16 bv = (bf16)acc[mi][nf][r];
          const long long bh = bb * 8 + hh;
          if (mat == 0)      qo[(bh * 2048 + n) * 64 + dh] = bv;
          else if (mat == 1) ko[(bh * 2048 + n) * 64 + dh] = bv;
          else               vo[(bh * 64 + dh) * 2048 + n] = bv;
        }
      }
    }
  } else {
#pragma unroll
    for (int nf = 0; nf < 4; ++nf) {
      const int col = (int)coltile + 64 * wc + nf * 16 + l15;
      const float bias = bo[col];
#pragma unroll
      for (int mi = 0; mi < 4; ++mi)
#pragma unroll
        for (int r = 0; r < 4; ++r) {
          const long long R = rowtile + 64 * wr + mi * 16 + lq * 4 + r;
          outp[R * 512 + col] = acc[mi][nf][r] + bias;
        }
    }
  }
}

// ---- flash attention v4 ----
// block = (b,h, qtile of 64 rows); 256 thr = 4 waves x 16 q-rows.
// Swapped QK^T (q on lane&15): f32x4 mask loads, in-register P via
// cvt_pk_bf16 + permlane16/32_swap (no P LDS). K via LDS double-buffer
// (gload_lds, XOR-swizzled src). V + mask straight from global (L1/L2;
// mask nontemporal so it doesn't evict V). XCD swizzle: same (b,qt)
// across h on one XCD (mask L2 reuse); same b per XCD (K/V L2 reuse).
__global__ __launch_bounds__(256, 4) void k_attn(
    const bf16* __restrict__ qb, const bf16* __restrict__ kb, const bf16* __restrict__ vt,
    const float* __restrict__ mask, bf16* __restrict__ ao) {
  __shared__ __align__(16) bf16 kls[2][64 * 64];   // 16 KB K double buffer
  const int tid = threadIdx.x;
  const int wid = tid >> 6, lane = tid & 63;
  const int l15 = lane & 15, lq = lane >> 4;
  const int p = blockIdx.x;
  const int xcd = p & 7, rr = p >> 3;
  const int g = xcd * 32 + (rr >> 3), h = rr & 7;
  const int b = g >> 5, qt = g & 31;
  const long long bh = b * 8 + h;
  const bf16* Q = qb + bh * (2048ll * 64);
  const bf16* K = kb + bh * (2048ll * 64);
  const bf16* V = vt + bh * (64ll * 2048);
  const int qrow0 = qt * 64 + wid * 16;
  const float* mptr = mask + ((long long)b * 2048 + qrow0 + l15) * 2048 + lq * 4;
  const bf16* Vr[4];
#pragma unroll
  for (int nf = 0; nf < 4; ++nf) Vr[nf] = V + (nf * 16 + l15) * 2048 + lq * 8;

  // K staging: 256 thr x 2 x 16B = 8KB tile; inverse-swizzled global src
  const int sr0 = tid >> 3, sr1 = sr0 + 32;
  const int sc0 = (tid & 7) ^ (sr0 & 7), sc1 = (tid & 7) ^ (sr1 & 7);
  const bf16* kg0 = K + sr0 * 64 + sc0 * 8;
  const bf16* kg1 = K + sr1 * 64 + sc1 * 8;
  bf16* kd0[2] = { &kls[0][tid * 8], &kls[1][tid * 8] };
  bf16* kd1[2] = { &kls[0][2048 + tid * 8], &kls[1][2048 + tid * 8] };

  bf16x8 qf[2];
#pragma unroll
  for (int ks = 0; ks < 2; ++ks)
    qf[ks] = *(const bf16x8*)(Q + (qrow0 + l15) * 64 + ks * 32 + lq * 8);

  f32x4 o[4] = {};
  float lsum = 0.f;
  f32x4 mA[4], mB[4];

  auto stageK = [&](int buf, int jt) {
    gload_lds16(kg0 + jt * 4096, kd0[buf]);
    gload_lds16(kg1 + jt * 4096, kd1[buf]);
  };
  auto mload = [&](f32x4 (&m)[4], int jb) {
#pragma unroll
    for (int nf = 0; nf < 4; ++nf)
      m[nf] = __builtin_nontemporal_load((const f32x4*)(mptr + jb + nf * 16));
  };

  auto compute = [&](const bf16* kbL, const f32x4 (&m)[4], int jb) {
    // V loads first: L1/L2 latency hides under QK^T + exp
    bf16x8 vf0[4], vf1[4];
#pragma unroll
    for (int nf = 0; nf < 4; ++nf) {
      vf0[nf] = *(const bf16x8*)(Vr[nf] + jb);
      vf1[nf] = *(const bf16x8*)(Vr[nf] + jb + 32);
    }
    // QK^T swapped: A=K (rows n), B=Q (cols q) -> s[nf][r]: q=l15, n=nf*16+lq*4+r
    f32x4 s[4];
#pragma unroll
    for (int nf = 0; nf < 4; ++nf) {
      const int row = nf * 16 + l15;
      const bf16x8 kf = *(const bf16x8*)(kbL + row * 64 + ((lq ^ (row & 7)) << 3));
      f32x4 z = {0.f, 0.f, 0.f, 0.f};
      s[nf] = mfma16(kf, qf[0], z);
    }
#pragma unroll
    for (int nf = 0; nf < 4; ++nf) {
      const int row = nf * 16 + l15;
      const bf16x8 kf = *(const bf16x8*)(kbL + row * 64 + (((4 + lq) ^ (row & 7)) << 3));
      s[nf] = mfma16(kf, qf[1], s[nf]);
    }
    // p = exp2(s * SC2*(1+mask)); pack to bf16 pairs (consecutive n)
    unsigned w[4][2];
#pragma unroll
    for (int nf = 0; nf < 4; ++nf) {
      float mp0 = fmaf(m[nf][0], SC2, SC2);
      float mp1 = fmaf(m[nf][1], SC2, SC2);
      float mp2 = fmaf(m[nf][2], SC2, SC2);
      float mp3 = fmaf(m[nf][3], SC2, SC2);
      float pe0 = EXP2(s[nf][0] * mp0);
      float pe1 = EXP2(s[nf][1] * mp1);
      float pe2 = EXP2(s[nf][2] * mp2);
      float pe3 = EXP2(s[nf][3] * mp3);
      lsum += ((pe0 + pe1) + (pe2 + pe3));
      w[nf][0] = cvt_pk_bf16(pe0, pe1);
      w[nf][1] = cvt_pk_bf16(pe2, pe3);
    }
    // exchange to PV A-fragment: pa[ks2] = P[q=l15][n = jb+ks2*32+lq*8+j]
    unsigned pa0[4], pa1[4];
#ifdef HAVE_PLSWAP
#pragma unroll
    for (int t = 0; t < 2; ++t) {
      auto sA = __builtin_amdgcn_permlane32_swap(w[0][t], w[1][t], false, false);
      auto sB = __builtin_amdgcn_permlane16_swap(sA[0], sA[1], false, false);
      pa0[t] = sB[0]; pa0[t + 2] = sB[1];
      auto sC = __builtin_amdgcn_permlane32_swap(w[2][t], w[3][t], false, false);
      auto sD = __builtin_amdgcn_permlane16_swap(sC[0], sC[1], false, false);
      pa1[t] = sD[0]; pa1[t + 2] = sD[1];
    }
#else
    {
      const int basel = l15 + ((lq & 1) << 5);
#pragma unroll
      for (int t = 0; t < 2; ++t) {
        int sel0 = (lq & 2) ? (int)w[1][t] : (int)w[0][t];
        int sel1 = (lq & 2) ? (int)w[3][t] : (int)w[2][t];
        pa0[t]     = (unsigned)__shfl(sel0, basel);
        pa0[t + 2] = (unsigned)__shfl(sel0, basel + 16);
        pa1[t]     = (unsigned)__shfl(sel1, basel);
        pa1[t + 2] = (unsigned)__shfl(sel1, basel + 16);
      }
    }
#endif
    u32x4 ua = {pa0[0], pa0[1], pa0[2], pa0[3]};
    u32x4 ub = {pa1[0], pa1[1], pa1[2], pa1[3]};
    const bf16x8 paA = __builtin_bit_cast(bf16x8, ua);
    const bf16x8 paB = __builtin_bit_cast(bf16x8, ub);
    // PV: D row = q(lq*4+r), col = dh(l15) -> standard output layout
#pragma unroll
    for (int nf = 0; nf < 4; ++nf) o[nf] = mfma16(paA, vf0[nf], o[nf]);
#pragma unroll
    for (int nf = 0; nf < 4; ++nf) o[nf] = mfma16(paB, vf1[nf], o[nf]);
  };

  // prologue
  stageK(0, 0);
  mload(mA, 0);
  __syncthreads();

  for (int jt = 0; jt < 32; jt += 2) {
    stageK(1, jt + 1);
    mload(mB, (jt + 1) * 64);
    compute(&kls[0][0], mA, jt * 64);
    __syncthreads();
    if (jt + 2 < 32) {
      stageK(0, jt + 2);
      mload(mA, (jt + 2) * 64);
    }
    compute(&kls[1][0], mB, (jt + 1) * 64);
    __syncthreads();
  }

  // lsum holds partial for q=l15 over this lane's n-slice; reduce across lq
  lsum += __shfl_xor(lsum, 16);
  lsum += __shfl_xor(lsum, 32);
  const float rinv = 1.0f / lsum;
  float rv[4];
#pragma unroll
  for (int r = 0; r < 4; ++r)
    rv[r] = __shfl(rinv, ((lane & 48) >> 2) + r);   // rinv for q = lq*4+r
#pragma unroll
  for (int nf = 0; nf < 4; ++nf)
#pragma unroll
    for (int r = 0; r < 4; ++r) {
      const long long rowg = (long long)b * 2048 + qrow0 + lq * 4 + r;
      ao[rowg * 512 + h * 64 + nf * 16 + l15] = (bf16)(o[nf][r] * rv[r]);
    }
}

extern "C" void kernel_launch(void* const* d_in, const int* in_sizes, int n_in,
                              void* d_out, int out_size, void* d_ws, size_t ws_size,
                              hipStream_t stream) {
  const float* x    = (const float*)d_in[0];
  const float* mask = (const float*)d_in[1];
  const float* Wq   = (const float*)d_in[2];
  const float* Wk   = (const float*)d_in[3];
  const float* Wv   = (const float*)d_in[4];
  const float* Wo   = (const float*)d_in[5];
  const float* bo   = (const float*)d_in[6];
  float* out = (float*)d_out;
  char* ws = (char*)d_ws;

  const size_t SZ_XB = (size_t)16384 * 512 * 2;
  const size_t SZ_W3 = (size_t)1536 * 512 * 2;
  const size_t SZ_WO = (size_t)512 * 512 * 2;
  const size_t SZ_T  = (size_t)64 * 2048 * 64 * 2;

  bf16* xb    = (bf16*)ws;
  bf16* wqkvT = (bf16*)(ws + SZ_XB);
  bf16* woT   = (bf16*)(ws + SZ_XB + SZ_W3);
  bf16* qbuf  = (bf16*)(ws + SZ_XB + SZ_W3 + SZ_WO);
  bf16* kbuf  = (bf16*)((char*)qbuf + SZ_T);
  bf16* vtb   = (bf16*)((char*)kbuf + SZ_T);
  bf16* aob   = xb;  // x dead after QKV GEMM

  k_cvt_x<<<dim3(4096), dim3(256), 0, stream>>>(x, xb);
  k_wt<<<dim3(8, 8), dim3(256), 0, stream>>>(Wq, wqkvT);
  k_wt<<<dim3(8, 8), dim3(256), 0, stream>>>(Wk, wqkvT + 512 * 512);
  k_wt<<<dim3(8, 8), dim3(256), 0, stream>>>(Wv, wqkvT + 2 * 512 * 512);
  k_wt<<<dim3(8, 8), dim3(256), 0, stream>>>(Wo, woT);
  k_gemm<0><<<dim3(128, 12), dim3(256), 0, stream>>>(xb, wqkvT, qbuf, kbuf, vtb, nullptr, nullptr);
  k_attn<<<dim3(2048), dim3(256), 0, stream>>>(qbuf, kbuf, vtb, mask, aob);
  k_gemm<1><<<dim3(128, 4), dim3(256), 0, stream>>>(aob, woT, nullptr, nullptr, nullptr, out, bo);
}

// Round 6
// 250.281 us; speedup vs baseline: 1.9342x; 1.9342x over previous
//
#include <hip/hip_runtime.h>

typedef __bf16 bf16;
typedef __bf16 bf16x8 __attribute__((ext_vector_type(8)));
typedef float  f32x4  __attribute__((ext_vector_type(4)));
typedef unsigned u32x4 __attribute__((ext_vector_type(4)));

#define B_  8
#define N_  2048
#define D_  512
#define H_  8
#define DH_ 64
static constexpr float SC2 = 0.18033688011112042f; // (1/8) * log2(e)

#if defined(__has_builtin)
#if __has_builtin(__builtin_amdgcn_exp2f)
#define EXP2(x) __builtin_amdgcn_exp2f(x)
#else
#define EXP2(x) exp2f(x)
#endif
#else
#define EXP2(x) exp2f(x)
#endif

#if defined(__has_builtin)
#if __has_builtin(__builtin_amdgcn_permlane32_swap) && __has_builtin(__builtin_amdgcn_permlane16_swap)
#define HAVE_PLSWAP 1
#endif
#endif

__device__ __forceinline__ f32x4 mfma16(bf16x8 a, bf16x8 b, f32x4 c) {
  return __builtin_amdgcn_mfma_f32_16x16x32_bf16(a, b, c, 0, 0, 0);
}

__device__ __forceinline__ void gload_lds16(const void* g, void* l) {
  __builtin_amdgcn_global_load_lds((__attribute__((address_space(1))) void*)g,
                                   (__attribute__((address_space(3))) void*)l, 16, 0, 0);
}

__device__ __forceinline__ unsigned cvt_pk_bf16(float lo, float hi) {
  unsigned r;
  asm("v_cvt_pk_bf16_f32 %0, %1, %2" : "=v"(r) : "v"(lo), "v"(hi));
  return r;
}

// ---- convert x (f32) -> bf16, 8 elems/thread ----
__global__ void k_cvt_x(const float* __restrict__ x, bf16* __restrict__ xb) {
  int i = blockIdx.x * blockDim.x + threadIdx.x;
  const float4* p = (const float4*)x;
  float4 a = p[2*i], b = p[2*i+1];
  bf16x8 o;
  o[0]=(bf16)a.x; o[1]=(bf16)a.y; o[2]=(bf16)a.z; o[3]=(bf16)a.w;
  o[4]=(bf16)b.x; o[5]=(bf16)b.y; o[6]=(bf16)b.z; o[7]=(bf16)b.w;
  ((bf16x8*)xb)[i] = o;
}

// ---- transpose-convert one 512x512 f32 weight -> bf16 W^T ----
__global__ void k_wt(const float* __restrict__ w, bf16* __restrict__ wt) {
  __shared__ float t[64][65];
  const int c0 = blockIdx.x * 64, k0 = blockIdx.y * 64;
  const int r = threadIdx.x >> 2, q4 = (threadIdx.x & 3) * 16;
#pragma unroll
  for (int j = 0; j < 16; j += 4) {
    float4 v = *(const float4*)(w + (k0 + r) * 512 + c0 + q4 + j);
    t[r][q4+j] = v.x; t[r][q4+j+1] = v.y; t[r][q4+j+2] = v.z; t[r][q4+j+3] = v.w;
  }
  __syncthreads();
  const int c = threadIdx.x >> 2, kq = (threadIdx.x & 3) * 16;
  bf16x8 o0, o1;
#pragma unroll
  for (int j = 0; j < 8; ++j) { o0[j] = (bf16)t[kq+j][c]; o1[j] = (bf16)t[kq+8+j][c]; }
  *(bf16x8*)(wt + (c0 + c) * 512 + k0 + kq) = o0;
  *(bf16x8*)(wt + (c0 + c) * 512 + k0 + kq + 8) = o1;
}

// ---- 128x128 tile GEMM, K=512 ----
template<int MODE>
__global__ void k_gemm(const bf16* __restrict__ A, const bf16* __restrict__ Bt,
                       bf16* __restrict__ qo, bf16* __restrict__ ko, bf16* __restrict__ vo,
                       float* __restrict__ outp, const float* __restrict__ bo) {
  __shared__ bf16 lA[128 * 64];
  __shared__ bf16 lB[128 * 64];
  const int tid = threadIdx.x;
  const int wid = tid >> 6, lane = tid & 63;
  const int l15 = lane & 15, lq = lane >> 4;
  const int wr = wid >> 1, wc = wid & 1;
  const long long rowtile = (long long)blockIdx.x * 128;
  const long long coltile = (long long)blockIdx.y * 128;

  const bf16* gA[4]; const bf16* gB[4];
  bf16* lAc[4]; bf16* lBc[4];
#pragma unroll
  for (int i = 0; i < 4; ++i) {
    int ci = wid * 4 + i;
    int row = ci * 8 + (lane >> 3);
    int c8 = (lane & 7) ^ (row & 7);
    gA[i] = A + (rowtile + row) * 512 + c8 * 8;
    gB[i] = Bt + (coltile + row) * 512 + c8 * 8;
    lAc[i] = &lA[ci * 512];
    lBc[i] = &lB[ci * 512];
  }
  unsigned aoff[4][2], boff[4][2];
#pragma unroll
  for (int mi = 0; mi < 4; ++mi) {
#pragma unroll
    for (int ks = 0; ks < 2; ++ks) {
      int R = l15 + 16 * mi + 64 * wr;
      aoff[mi][ks] = R * 128 + ((((ks << 2) | lq) ^ (R & 7)) << 4);
      int Rb = l15 + 16 * mi + 64 * wc;
      boff[mi][ks] = Rb * 128 + ((((ks << 2) | lq) ^ (Rb & 7)) << 4);
    }
  }
  f32x4 acc[4][4] = {};
  for (int kt = 0; kt < 8; ++kt) {
#pragma unroll
    for (int i = 0; i < 4; ++i) gload_lds16(gA[i], lAc[i]);
#pragma unroll
    for (int i = 0; i < 4; ++i) gload_lds16(gB[i], lBc[i]);
#pragma unroll
    for (int i = 0; i < 4; ++i) { gA[i] += 64; gB[i] += 64; }
    __syncthreads();
#pragma unroll
    for (int ks = 0; ks < 2; ++ks) {
      bf16x8 af[4], bfr[4];
#pragma unroll
      for (int mi = 0; mi < 4; ++mi) af[mi] = *(const bf16x8*)((const char*)lA + aoff[mi][ks]);
#pragma unroll
      for (int nf = 0; nf < 4; ++nf) bfr[nf] = *(const bf16x8*)((const char*)lB + boff[nf][ks]);
#pragma unroll
      for (int mi = 0; mi < 4; ++mi)
#pragma unroll
        for (int nf = 0; nf < 4; ++nf)
          acc[mi][nf] = mfma16(af[mi], bfr[nf], acc[mi][nf]);
    }
    __syncthreads();
  }
  if (MODE == 0) {
#pragma unroll
    for (int nf = 0; nf < 4; ++nf) {
      const int col = (int)coltile + 64 * wc + nf * 16 + l15;
      const int mat = col >> 9, c5 = col & 511, hh = c5 >> 6, dh = c5 & 63;
#pragma unroll
      for (int mi = 0; mi < 4; ++mi) {
#pragma unroll
        for (int r = 0; r < 4; ++r) {
          const int R = (int)rowtile + 64 * wr + mi * 16 + lq * 4 + r;
          const int bb = R >> 11, n = R & 2047;
          const bf16 bv = (bf16)acc[mi][nf][r];
          const long long bh = bb * 8 + hh;
          if (mat == 0)      qo[(bh * 2048 + n) * 64 + dh] = bv;
          else if (mat == 1) ko[(bh * 2048 + n) * 64 + dh] = bv;
          else               vo[(bh * 64 + dh) * 2048 + n] = bv;
        }
      }
    }
  } else {
#pragma unroll
    for (int nf = 0; nf < 4; ++nf) {
      const int col = (int)coltile + 64 * wc + nf * 16 + l15;
      const float bias = bo[col];
#pragma unroll
      for (int mi = 0; mi < 4; ++mi)
#pragma unroll
        for (int r = 0; r < 4; ++r) {
          const long long R = rowtile + 64 * wr + mi * 16 + lq * 4 + r;
          outp[R * 512 + col] = acc[mi][nf][r] + bias;
        }
    }
  }
}

// ---- flash attention v6 ----
// block = (b,h, qtile of 128 rows); 512 thr = 8 waves x 16 q-rows.
// K AND V in LDS double-buffer (gload_lds, XOR-swizzled src; r3-proven).
// Swapped QK^T -> in-register P via cvt_pk + permlane (r5-proven algebra).
// Mask: plain f32x4 loads, reg double-buffered (L2-shared across h-blocks).
// waves_per_eu(4,4): pin VGPR budget at 128 so loads actually pipeline
// (r5's compiler chose 64 VGPRs chasing occupancy -> serialized loads).
__global__ __attribute__((amdgpu_flat_work_group_size(512, 512),
                          amdgpu_waves_per_eu(4, 4))) void k_attn(
    const bf16* __restrict__ qb, const bf16* __restrict__ kb, const bf16* __restrict__ vt,
    const float* __restrict__ mask, bf16* __restrict__ ao) {
  __shared__ __align__(16) bf16 kvls[2][2][64 * 64];   // [buf][K/V], 32 KB
  const int tid = threadIdx.x;
  const int wid = tid >> 6, lane = tid & 63;
  const int l15 = lane & 15, lq = lane >> 4;
  const int p = blockIdx.x;
  const int xcd = p & 7, kk = p >> 3;
  const int g = xcd * 16 + (kk >> 3), h = kk & 7;
  const int b = g >> 4, qt = g & 15;
  const long long bh = b * 8 + h;
  const bf16* Q = qb + bh * (2048ll * 64);
  const bf16* K = kb + bh * (2048ll * 64);
  const bf16* V = vt + bh * (64ll * 2048);
  const int qrow0 = qt * 128 + wid * 16;
  const float* mptr = mask + ((long long)b * 2048 + qrow0 + l15) * 2048 + lq * 4;

  // staging: 512 thr x 16B = one 8KB tile each for K and V; swizzled source
  const int srow = tid >> 3;
  const int sc = (tid & 7) ^ (srow & 7);
  const bf16* kg = K + srow * 64 + sc * 8;     // K rows = n (stride 64)
  const bf16* vg = V + srow * 2048 + sc * 8;   // V^T rows = dh (stride 2048)

  bf16x8 qf[2];
#pragma unroll
  for (int ks = 0; ks < 2; ++ks)
    qf[ks] = *(const bf16x8*)(Q + (qrow0 + l15) * 64 + ks * 32 + lq * 8);

  f32x4 o[4] = {};
  float lsum = 0.f;
  f32x4 mA[4], mB[4];

  auto stageKV = [&](int buf, int jt) {
    gload_lds16(kg + jt * 4096, &kvls[buf][0][tid * 8]);
    gload_lds16(vg + jt * 64,   &kvls[buf][1][tid * 8]);
  };
  auto mload = [&](f32x4 (&m)[4], int jb) {
#pragma unroll
    for (int nf = 0; nf < 4; ++nf)
      m[nf] = *(const f32x4*)(mptr + jb + nf * 16);
  };

  auto compute = [&](int buf, const f32x4 (&m)[4]) {
    const bf16* kbL = &kvls[buf][0][0];
    const bf16* vbL = &kvls[buf][1][0];
    // QK^T swapped: A=K (rows n), B=Q (cols q) -> s[nf][r]: q=l15, n=nf*16+lq*4+r
    f32x4 s[4];
#pragma unroll
    for (int nf = 0; nf < 4; ++nf) {
      const int row = nf * 16 + l15;
      const bf16x8 kf = *(const bf16x8*)(kbL + row * 64 + ((lq ^ (row & 7)) << 3));
      f32x4 z = {0.f, 0.f, 0.f, 0.f};
      s[nf] = mfma16(kf, qf[0], z);
    }
#pragma unroll
    for (int nf = 0; nf < 4; ++nf) {
      const int row = nf * 16 + l15;
      const bf16x8 kf = *(const bf16x8*)(kbL + row * 64 + (((4 + lq) ^ (row & 7)) << 3));
      s[nf] = mfma16(kf, qf[1], s[nf]);
    }
    // p = exp2(s * SC2*(1+mask)); pack to bf16 pairs (consecutive n)
    unsigned w[4][2];
#pragma unroll
    for (int nf = 0; nf < 4; ++nf) {
      float mp0 = fmaf(m[nf][0], SC2, SC2);
      float mp1 = fmaf(m[nf][1], SC2, SC2);
      float mp2 = fmaf(m[nf][2], SC2, SC2);
      float mp3 = fmaf(m[nf][3], SC2, SC2);
      float pe0 = EXP2(s[nf][0] * mp0);
      float pe1 = EXP2(s[nf][1] * mp1);
      float pe2 = EXP2(s[nf][2] * mp2);
      float pe3 = EXP2(s[nf][3] * mp3);
      lsum += ((pe0 + pe1) + (pe2 + pe3));
      w[nf][0] = cvt_pk_bf16(pe0, pe1);
      w[nf][1] = cvt_pk_bf16(pe2, pe3);
    }
    // exchange to PV A-fragment: pa[t] = P[q=l15][n = ks2*32+lq*8+2t..]
    unsigned pa0[4], pa1[4];
#ifdef HAVE_PLSWAP
#pragma unroll
    for (int t = 0; t < 2; ++t) {
      auto sA = __builtin_amdgcn_permlane32_swap(w[0][t], w[1][t], false, false);
      auto sB = __builtin_amdgcn_permlane16_swap(sA[0], sA[1], false, false);
      pa0[t] = sB[0]; pa0[t + 2] = sB[1];
      auto sC = __builtin_amdgcn_permlane32_swap(w[2][t], w[3][t], false, false);
      auto sD = __builtin_amdgcn_permlane16_swap(sC[0], sC[1], false, false);
      pa1[t] = sD[0]; pa1[t + 2] = sD[1];
    }
#else
    {
      const int basel = l15 + ((lq & 1) << 5);
#pragma unroll
      for (int t = 0; t < 2; ++t) {
        int sel0 = (lq & 2) ? (int)w[1][t] : (int)w[0][t];
        int sel1 = (lq & 2) ? (int)w[3][t] : (int)w[2][t];
        pa0[t]     = (unsigned)__shfl(sel0, basel);
        pa0[t + 2] = (unsigned)__shfl(sel0, basel + 16);
        pa1[t]     = (unsigned)__shfl(sel1, basel);
        pa1[t + 2] = (unsigned)__shfl(sel1, basel + 16);
      }
    }
#endif
    u32x4 ua = {pa0[0], pa0[1], pa0[2], pa0[3]};
    u32x4 ub = {pa1[0], pa1[1], pa1[2], pa1[3]};
    const bf16x8 paA = __builtin_bit_cast(bf16x8, ua);
    const bf16x8 paB = __builtin_bit_cast(bf16x8, ub);
    // PV: B = V^T tile rows dh; D row = q(lq*4+r), col = dh(l15)
#pragma unroll
    for (int nf = 0; nf < 4; ++nf) {
      const int row = nf * 16 + l15;
      const bf16x8 vf = *(const bf16x8*)(vbL + row * 64 + ((lq ^ (row & 7)) << 3));
      o[nf] = mfma16(paA, vf, o[nf]);
    }
#pragma unroll
    for (int nf = 0; nf < 4; ++nf) {
      const int row = nf * 16 + l15;
      const bf16x8 vf = *(const bf16x8*)(vbL + row * 64 + (((4 + lq) ^ (row & 7)) << 3));
      o[nf] = mfma16(paB, vf, o[nf]);
    }
  };

  // prologue
  stageKV(0, 0);
  mload(mA, 0);
  __syncthreads();

  for (int jt = 0; jt < 32; jt += 2) {
    stageKV(1, jt + 1);
    mload(mB, (jt + 1) * 64);
    compute(0, mA);
    __syncthreads();
    if (jt + 2 < 32) {
      stageKV(0, jt + 2);
      mload(mA, (jt + 2) * 64);
    }
    compute(1, mB);
    __syncthreads();
  }

  // lsum: partial for q=l15 over this lane's n-slice; reduce across the 4 lq groups
  lsum += __shfl_xor(lsum, 16);
  lsum += __shfl_xor(lsum, 32);
  const float rinv = 1.0f / lsum;
  float rv[4];
#pragma unroll
  for (int r = 0; r < 4; ++r)
    rv[r] = __shfl(rinv, ((lane & 48) >> 2) + r);   // rinv of q = lq*4+r
#pragma unroll
  for (int nf = 0; nf < 4; ++nf)
#pragma unroll
    for (int r = 0; r < 4; ++r) {
      const long long rowg = (long long)b * 2048 + qrow0 + lq * 4 + r;
      ao[rowg * 512 + h * 64 + nf * 16 + l15] = (bf16)(o[nf][r] * rv[r]);
    }
}

extern "C" void kernel_launch(void* const* d_in, const int* in_sizes, int n_in,
                              void* d_out, int out_size, void* d_ws, size_t ws_size,
                              hipStream_t stream) {
  const float* x    = (const float*)d_in[0];
  const float* mask = (const float*)d_in[1];
  const float* Wq   = (const float*)d_in[2];
  const float* Wk   = (const float*)d_in[3];
  const float* Wv   = (const float*)d_in[4];
  const float* Wo   = (const float*)d_in[5];
  const float* bo   = (const float*)d_in[6];
  float* out = (float*)d_out;
  char* ws = (char*)d_ws;

  const size_t SZ_XB = (size_t)16384 * 512 * 2;
  const size_t SZ_W3 = (size_t)1536 * 512 * 2;
  const size_t SZ_WO = (size_t)512 * 512 * 2;
  const size_t SZ_T  = (size_t)64 * 2048 * 64 * 2;

  bf16* xb    = (bf16*)ws;
  bf16* wqkvT = (bf16*)(ws + SZ_XB);
  bf16* woT   = (bf16*)(ws + SZ_XB + SZ_W3);
  bf16* qbuf  = (bf16*)(ws + SZ_XB + SZ_W3 + SZ_WO);
  bf16* kbuf  = (bf16*)((char*)qbuf + SZ_T);
  bf16* vtb   = (bf16*)((char*)kbuf + SZ_T);
  bf16* aob   = xb;  // x dead after QKV GEMM

  k_cvt_x<<<dim3(4096), dim3(256), 0, stream>>>(x, xb);
  k_wt<<<dim3(8, 8), dim3(256), 0, stream>>>(Wq, wqkvT);
  k_wt<<<dim3(8, 8), dim3(256), 0, stream>>>(Wk, wqkvT + 512 * 512);
  k_wt<<<dim3(8, 8), dim3(256), 0, stream>>>(Wv, wqkvT + 2 * 512 * 512);
  k_wt<<<dim3(8, 8), dim3(256), 0, stream>>>(Wo, woT);
  k_gemm<0><<<dim3(128, 12), dim3(256), 0, stream>>>(xb, wqkvT, qbuf, kbuf, vtb, nullptr, nullptr);
  k_attn<<<dim3(1024), dim3(512), 0, stream>>>(qbuf, kbuf, vtb, mask, aob);
  k_gemm<1><<<dim3(128, 4), dim3(256), 0, stream>>>(aob, woT, nullptr, nullptr, nullptr, out, bo);
}

// Round 7
// 249.649 us; speedup vs baseline: 1.9391x; 1.0025x over previous
//
#include <hip/hip_runtime.h>

typedef __bf16 bf16;
typedef __bf16 bf16x8 __attribute__((ext_vector_type(8)));
typedef float  f32x4  __attribute__((ext_vector_type(4)));
typedef unsigned u32x4 __attribute__((ext_vector_type(4)));

#define B_  8
#define N_  2048
#define D_  512
#define H_  8
#define DH_ 64
static constexpr float SC2 = 0.18033688011112042f; // (1/8) * log2(e)

#if defined(__has_builtin)
#if __has_builtin(__builtin_amdgcn_exp2f)
#define EXP2(x) __builtin_amdgcn_exp2f(x)
#else
#define EXP2(x) exp2f(x)
#endif
#else
#define EXP2(x) exp2f(x)
#endif

#if defined(__has_builtin)
#if __has_builtin(__builtin_amdgcn_permlane32_swap) && __has_builtin(__builtin_amdgcn_permlane16_swap)
#define HAVE_PLSWAP 1
#endif
#endif

__device__ __forceinline__ f32x4 mfma16(bf16x8 a, bf16x8 b, f32x4 c) {
  return __builtin_amdgcn_mfma_f32_16x16x32_bf16(a, b, c, 0, 0, 0);
}

__device__ __forceinline__ void gload_lds16(const void* g, void* l) {
  __builtin_amdgcn_global_load_lds((__attribute__((address_space(1))) void*)g,
                                   (__attribute__((address_space(3))) void*)l, 16, 0, 0);
}

__device__ __forceinline__ unsigned cvt_pk_bf16(float lo, float hi) {
  unsigned r;
  asm("v_cvt_pk_bf16_f32 %0, %1, %2" : "=v"(r) : "v"(lo), "v"(hi));
  return r;
}

// ---- convert x (f32) -> bf16, 8 elems/thread ----
__global__ void k_cvt_x(const float* __restrict__ x, bf16* __restrict__ xb) {
  int i = blockIdx.x * blockDim.x + threadIdx.x;
  const float4* p = (const float4*)x;
  float4 a = p[2*i], b = p[2*i+1];
  bf16x8 o;
  o[0]=(bf16)a.x; o[1]=(bf16)a.y; o[2]=(bf16)a.z; o[3]=(bf16)a.w;
  o[4]=(bf16)b.x; o[5]=(bf16)b.y; o[6]=(bf16)b.z; o[7]=(bf16)b.w;
  ((bf16x8*)xb)[i] = o;
}

// ---- transpose-convert one 512x512 f32 weight -> bf16 W^T ----
__global__ void k_wt(const float* __restrict__ w, bf16* __restrict__ wt) {
  __shared__ float t[64][65];
  const int c0 = blockIdx.x * 64, k0 = blockIdx.y * 64;
  const int r = threadIdx.x >> 2, q4 = (threadIdx.x & 3) * 16;
#pragma unroll
  for (int j = 0; j < 16; j += 4) {
    float4 v = *(const float4*)(w + (k0 + r) * 512 + c0 + q4 + j);
    t[r][q4+j] = v.x; t[r][q4+j+1] = v.y; t[r][q4+j+2] = v.z; t[r][q4+j+3] = v.w;
  }
  __syncthreads();
  const int c = threadIdx.x >> 2, kq = (threadIdx.x & 3) * 16;
  bf16x8 o0, o1;
#pragma unroll
  for (int j = 0; j < 8; ++j) { o0[j] = (bf16)t[kq+j][c]; o1[j] = (bf16)t[kq+8+j][c]; }
  *(bf16x8*)(wt + (c0 + c) * 512 + k0 + kq) = o0;
  *(bf16x8*)(wt + (c0 + c) * 512 + k0 + kq + 8) = o1;
}

// ---- 128x128 tile GEMM, K=512 ----
template<int MODE>
__global__ void k_gemm(const bf16* __restrict__ A, const bf16* __restrict__ Bt,
                       bf16* __restrict__ qo, bf16* __restrict__ ko, bf16* __restrict__ vo,
                       float* __restrict__ outp, const float* __restrict__ bo) {
  __shared__ bf16 lA[128 * 64];
  __shared__ bf16 lB[128 * 64];
  const int tid = threadIdx.x;
  const int wid = tid >> 6, lane = tid & 63;
  const int l15 = lane & 15, lq = lane >> 4;
  const int wr = wid >> 1, wc = wid & 1;
  const long long rowtile = (long long)blockIdx.x * 128;
  const long long coltile = (long long)blockIdx.y * 128;

  const bf16* gA[4]; const bf16* gB[4];
  bf16* lAc[4]; bf16* lBc[4];
#pragma unroll
  for (int i = 0; i < 4; ++i) {
    int ci = wid * 4 + i;
    int row = ci * 8 + (lane >> 3);
    int c8 = (lane & 7) ^ (row & 7);
    gA[i] = A + (rowtile + row) * 512 + c8 * 8;
    gB[i] = Bt + (coltile + row) * 512 + c8 * 8;
    lAc[i] = &lA[ci * 512];
    lBc[i] = &lB[ci * 512];
  }
  unsigned aoff[4][2], boff[4][2];
#pragma unroll
  for (int mi = 0; mi < 4; ++mi) {
#pragma unroll
    for (int ks = 0; ks < 2; ++ks) {
      int R = l15 + 16 * mi + 64 * wr;
      aoff[mi][ks] = R * 128 + ((((ks << 2) | lq) ^ (R & 7)) << 4);
      int Rb = l15 + 16 * mi + 64 * wc;
      boff[mi][ks] = Rb * 128 + ((((ks << 2) | lq) ^ (Rb & 7)) << 4);
    }
  }
  f32x4 acc[4][4] = {};
  for (int kt = 0; kt < 8; ++kt) {
#pragma unroll
    for (int i = 0; i < 4; ++i) gload_lds16(gA[i], lAc[i]);
#pragma unroll
    for (int i = 0; i < 4; ++i) gload_lds16(gB[i], lBc[i]);
#pragma unroll
    for (int i = 0; i < 4; ++i) { gA[i] += 64; gB[i] += 64; }
    __syncthreads();
#pragma unroll
    for (int ks = 0; ks < 2; ++ks) {
      bf16x8 af[4], bfr[4];
#pragma unroll
      for (int mi = 0; mi < 4; ++mi) af[mi] = *(const bf16x8*)((const char*)lA + aoff[mi][ks]);
#pragma unroll
      for (int nf = 0; nf < 4; ++nf) bfr[nf] = *(const bf16x8*)((const char*)lB + boff[nf][ks]);
#pragma unroll
      for (int mi = 0; mi < 4; ++mi)
#pragma unroll
        for (int nf = 0; nf < 4; ++nf)
          acc[mi][nf] = mfma16(af[mi], bfr[nf], acc[mi][nf]);
    }
    __syncthreads();
  }
  if (MODE == 0) {
#pragma unroll
    for (int nf = 0; nf < 4; ++nf) {
      const int col = (int)coltile + 64 * wc + nf * 16 + l15;
      const int mat = col >> 9, c5 = col & 511, hh = c5 >> 6, dh = c5 & 63;
#pragma unroll
      for (int mi = 0; mi < 4; ++mi) {
#pragma unroll
        for (int r = 0; r < 4; ++r) {
          const int R = (int)rowtile + 64 * wr + mi * 16 + lq * 4 + r;
          const int bb = R >> 11, n = R & 2047;
          const bf16 bv = (bf16)acc[mi][nf][r];
          const long long bh = bb * 8 + hh;
          if (mat == 0)      qo[(bh * 2048 + n) * 64 + dh] = bv;
          else if (mat == 1) ko[(bh * 2048 + n) * 64 + dh] = bv;
          else               vo[(bh * 64 + dh) * 2048 + n] = bv;
        }
      }
    }
  } else {
#pragma unroll
    for (int nf = 0; nf < 4; ++nf) {
      const int col = (int)coltile + 64 * wc + nf * 16 + l15;
      const float bias = bo[col];
#pragma unroll
      for (int mi = 0; mi < 4; ++mi)
#pragma unroll
        for (int r = 0; r < 4; ++r) {
          const long long R = rowtile + 64 * wr + mi * 16 + lq * 4 + r;
          outp[R * 512 + col] = acc[mi][nf][r] + bias;
        }
    }
  }
}

// ---- flash attention v7 ----
// Identical to v6 except: waves_per_eu min-only (4) -- v6's (4,4) max
// clamped the CU to 16 waves (2 blocks) at VGPR=56, which supports 8/EU.
// 4 resident blocks/CU -> enough TLP to drive the LDS pipe to its floor.
__global__ __attribute__((amdgpu_flat_work_group_size(512, 512),
                          amdgpu_waves_per_eu(4))) void k_attn(
    const bf16* __restrict__ qb, const bf16* __restrict__ kb, const bf16* __restrict__ vt,
    const float* __restrict__ mask, bf16* __restrict__ ao) {
  __shared__ __align__(16) bf16 kvls[2][2][64 * 64];   // [buf][K/V], 32 KB
  const int tid = threadIdx.x;
  const int wid = tid >> 6, lane = tid & 63;
  const int l15 = lane & 15, lq = lane >> 4;
  const int p = blockIdx.x;
  const int xcd = p & 7, kk = p >> 3;
  const int g = xcd * 16 + (kk >> 3), h = kk & 7;
  const int b = g >> 4, qt = g & 15;
  const long long bh = b * 8 + h;
  const bf16* Q = qb + bh * (2048ll * 64);
  const bf16* K = kb + bh * (2048ll * 64);
  const bf16* V = vt + bh * (64ll * 2048);
  const int qrow0 = qt * 128 + wid * 16;
  const float* mptr = mask + ((long long)b * 2048 + qrow0 + l15) * 2048 + lq * 4;

  // staging: 512 thr x 16B = one 8KB tile each for K and V; swizzled source
  const int srow = tid >> 3;
  const int sc = (tid & 7) ^ (srow & 7);
  const bf16* kg = K + srow * 64 + sc * 8;     // K rows = n (stride 64)
  const bf16* vg = V + srow * 2048 + sc * 8;   // V^T rows = dh (stride 2048)

  bf16x8 qf[2];
#pragma unroll
  for (int ks = 0; ks < 2; ++ks)
    qf[ks] = *(const bf16x8*)(Q + (qrow0 + l15) * 64 + ks * 32 + lq * 8);

  f32x4 o[4] = {};
  float lsum = 0.f;
  f32x4 mA[4], mB[4];

  auto stageKV = [&](int buf, int jt) {
    gload_lds16(kg + jt * 4096, &kvls[buf][0][tid * 8]);
    gload_lds16(vg + jt * 64,   &kvls[buf][1][tid * 8]);
  };
  auto mload = [&](f32x4 (&m)[4], int jb) {
#pragma unroll
    for (int nf = 0; nf < 4; ++nf)
      m[nf] = *(const f32x4*)(mptr + jb + nf * 16);
  };

  auto compute = [&](int buf, const f32x4 (&m)[4]) {
    const bf16* kbL = &kvls[buf][0][0];
    const bf16* vbL = &kvls[buf][1][0];
    // QK^T swapped: A=K (rows n), B=Q (cols q) -> s[nf][r]: q=l15, n=nf*16+lq*4+r
    f32x4 s[4];
#pragma unroll
    for (int nf = 0; nf < 4; ++nf) {
      const int row = nf * 16 + l15;
      const bf16x8 kf = *(const bf16x8*)(kbL + row * 64 + ((lq ^ (row & 7)) << 3));
      f32x4 z = {0.f, 0.f, 0.f, 0.f};
      s[nf] = mfma16(kf, qf[0], z);
    }
#pragma unroll
    for (int nf = 0; nf < 4; ++nf) {
      const int row = nf * 16 + l15;
      const bf16x8 kf = *(const bf16x8*)(kbL + row * 64 + (((4 + lq) ^ (row & 7)) << 3));
      s[nf] = mfma16(kf, qf[1], s[nf]);
    }
    // p = exp2(s * SC2*(1+mask)); pack to bf16 pairs (consecutive n)
    unsigned w[4][2];
#pragma unroll
    for (int nf = 0; nf < 4; ++nf) {
      float mp0 = fmaf(m[nf][0], SC2, SC2);
      float mp1 = fmaf(m[nf][1], SC2, SC2);
      float mp2 = fmaf(m[nf][2], SC2, SC2);
      float mp3 = fmaf(m[nf][3], SC2, SC2);
      float pe0 = EXP2(s[nf][0] * mp0);
      float pe1 = EXP2(s[nf][1] * mp1);
      float pe2 = EXP2(s[nf][2] * mp2);
      float pe3 = EXP2(s[nf][3] * mp3);
      lsum += ((pe0 + pe1) + (pe2 + pe3));
      w[nf][0] = cvt_pk_bf16(pe0, pe1);
      w[nf][1] = cvt_pk_bf16(pe2, pe3);
    }
    // exchange to PV A-fragment: pa[t] = P[q=l15][n = ks2*32+lq*8+2t..]
    unsigned pa0[4], pa1[4];
#ifdef HAVE_PLSWAP
#pragma unroll
    for (int t = 0; t < 2; ++t) {
      auto sA = __builtin_amdgcn_permlane32_swap(w[0][t], w[1][t], false, false);
      auto sB = __builtin_amdgcn_permlane16_swap(sA[0], sA[1], false, false);
      pa0[t] = sB[0]; pa0[t + 2] = sB[1];
      auto sC = __builtin_amdgcn_permlane32_swap(w[2][t], w[3][t], false, false);
      auto sD = __builtin_amdgcn_permlane16_swap(sC[0], sC[1], false, false);
      pa1[t] = sD[0]; pa1[t + 2] = sD[1];
    }
#else
    {
      const int basel = l15 + ((lq & 1) << 5);
#pragma unroll
      for (int t = 0; t < 2; ++t) {
        int sel0 = (lq & 2) ? (int)w[1][t] : (int)w[0][t];
        int sel1 = (lq & 2) ? (int)w[3][t] : (int)w[2][t];
        pa0[t]     = (unsigned)__shfl(sel0, basel);
        pa0[t + 2] = (unsigned)__shfl(sel0, basel + 16);
        pa1[t]     = (unsigned)__shfl(sel1, basel);
        pa1[t + 2] = (unsigned)__shfl(sel1, basel + 16);
      }
    }
#endif
    u32x4 ua = {pa0[0], pa0[1], pa0[2], pa0[3]};
    u32x4 ub = {pa1[0], pa1[1], pa1[2], pa1[3]};
    const bf16x8 paA = __builtin_bit_cast(bf16x8, ua);
    const bf16x8 paB = __builtin_bit_cast(bf16x8, ub);
    // PV: B = V^T tile rows dh; D row = q(lq*4+r), col = dh(l15)
#pragma unroll
    for (int nf = 0; nf < 4; ++nf) {
      const int row = nf * 16 + l15;
      const bf16x8 vf = *(const bf16x8*)(vbL + row * 64 + ((lq ^ (row & 7)) << 3));
      o[nf] = mfma16(paA, vf, o[nf]);
    }
#pragma unroll
    for (int nf = 0; nf < 4; ++nf) {
      const int row = nf * 16 + l15;
      const bf16x8 vf = *(const bf16x8*)(vbL + row * 64 + (((4 + lq) ^ (row & 7)) << 3));
      o[nf] = mfma16(paB, vf, o[nf]);
    }
  };

  // prologue
  stageKV(0, 0);
  mload(mA, 0);
  __syncthreads();

  for (int jt = 0; jt < 32; jt += 2) {
    stageKV(1, jt + 1);
    mload(mB, (jt + 1) * 64);
    compute(0, mA);
    __syncthreads();
    if (jt + 2 < 32) {
      stageKV(0, jt + 2);
      mload(mA, (jt + 2) * 64);
    }
    compute(1, mB);
    __syncthreads();
  }

  // lsum: partial for q=l15 over this lane's n-slice; reduce across the 4 lq groups
  lsum += __shfl_xor(lsum, 16);
  lsum += __shfl_xor(lsum, 32);
  const float rinv = 1.0f / lsum;
  float rv[4];
#pragma unroll
  for (int r = 0; r < 4; ++r)
    rv[r] = __shfl(rinv, ((lane & 48) >> 2) + r);   // rinv of q = lq*4+r
#pragma unroll
  for (int nf = 0; nf < 4; ++nf)
#pragma unroll
    for (int r = 0; r < 4; ++r) {
      const long long rowg = (long long)b * 2048 + qrow0 + lq * 4 + r;
      ao[rowg * 512 + h * 64 + nf * 16 + l15] = (bf16)(o[nf][r] * rv[r]);
    }
}

extern "C" void kernel_launch(void* const* d_in, const int* in_sizes, int n_in,
                              void* d_out, int out_size, void* d_ws, size_t ws_size,
                              hipStream_t stream) {
  const float* x    = (const float*)d_in[0];
  const float* mask = (const float*)d_in[1];
  const float* Wq   = (const float*)d_in[2];
  const float* Wk   = (const float*)d_in[3];
  const float* Wv   = (const float*)d_in[4];
  const float* Wo   = (const float*)d_in[5];
  const float* bo   = (const float*)d_in[6];
  float* out = (float*)d_out;
  char* ws = (char*)d_ws;

  const size_t SZ_XB = (size_t)16384 * 512 * 2;
  const size_t SZ_W3 = (size_t)1536 * 512 * 2;
  const size_t SZ_WO = (size_t)512 * 512 * 2;
  const size_t SZ_T  = (size_t)64 * 2048 * 64 * 2;

  bf16* xb    = (bf16*)ws;
  bf16* wqkvT = (bf16*)(ws + SZ_XB);
  bf16* woT   = (bf16*)(ws + SZ_XB + SZ_W3);
  bf16* qbuf  = (bf16*)(ws + SZ_XB + SZ_W3 + SZ_WO);
  bf16* kbuf  = (bf16*)((char*)qbuf + SZ_T);
  bf16* vtb   = (bf16*)((char*)kbuf + SZ_T);
  bf16* aob   = xb;  // x dead after QKV GEMM

  k_cvt_x<<<dim3(4096), dim3(256), 0, stream>>>(x, xb);
  k_wt<<<dim3(8, 8), dim3(256), 0, stream>>>(Wq, wqkvT);
  k_wt<<<dim3(8, 8), dim3(256), 0, stream>>>(Wk, wqkvT + 512 * 512);
  k_wt<<<dim3(8, 8), dim3(256), 0, stream>>>(Wv, wqkvT + 2 * 512 * 512);
  k_wt<<<dim3(8, 8), dim3(256), 0, stream>>>(Wo, woT);
  k_gemm<0><<<dim3(128, 12), dim3(256), 0, stream>>>(xb, wqkvT, qbuf, kbuf, vtb, nullptr, nullptr);
  k_attn<<<dim3(1024), dim3(512), 0, stream>>>(qbuf, kbuf, vtb, mask, aob);
  k_gemm<1><<<dim3(128, 4), dim3(256), 0, stream>>>(aob, woT, nullptr, nullptr, nullptr, out, bo);
}